// Round 5
// baseline (258.176 us; speedup 1.0000x reference)
//
#include <hip/hip_runtime.h>
#include <math.h>

// Problem: x[128, 1, 512, 512] fp32.
//   pred = softplus(x); m = max(pred) per sample; out = m > 1e-8 ? pred/m : pred
// softplus is strictly monotone -> per-sample max of pred == softplus(raw max).
//
// R10: two-pass (fused line abandoned: R6 250 / R8 160 / R9 110 us vs
// two-pass ~98 us — cross-block join is structurally unprofitable here).
// New vs R7 (248 us e2e):
//  - Pass 1 computes softplus ONCE (VALU hidden under the HBM read flood),
//    packs to fp16, and stages it in the FIRST 32 KB of the block's own
//    64 KB output slot (out is scratch until pass 2). Also writes raw-max
//    partials as before.
//  - Pass 2 is a pure streamer: read own slot's 32 KB fp16 (L3-hot, half the
//    bytes of re-reading x), cvt+mul, write 64 KB fp32. No transcendentals.
//    Staged fp16 lines are overwritten while dirty in L3 -> no extra HBM
//    writeback. Intra-block RAW on the slot: load-all-to-regs, syncthreads,
//    then store. Inter-block: slots disjoint.
//  - fp16 adds ~5e-4 abs error post-scale; current margin 0.0039 << 2e-2.

#define PER_SAMPLE (512 * 512)                       // 262144 floats / sample
#define F4_PER_SAMPLE (PER_SAMPLE / 4)               // 65536 float4
#define BLOCKS_PER_SAMPLE 16
#define THREADS 256
#define F4_PER_BLOCK (F4_PER_SAMPLE / BLOCKS_PER_SAMPLE) // 4096 float4
#define F4_PER_THREAD (F4_PER_BLOCK / THREADS)           // 16 float4 / thread
#define BATCH 4
#define NBATCH (F4_PER_THREAD / BATCH)                   // 4
#define SLOT_BYTES (F4_PER_BLOCK * 16)                   // 64 KB per block

typedef float    f32x4 __attribute__((ext_vector_type(4)));
typedef _Float16 f16x4 __attribute__((ext_vector_type(4)));
typedef _Float16 f16x8 __attribute__((ext_vector_type(8)));

__device__ __forceinline__ float softplus_f(float x) {
    // max(x,0) + log1p(exp(-|x|)); abs err ~6e-8 << 2e-2 threshold.
    return fmaxf(x, 0.0f) + __logf(1.0f + __expf(-fabsf(x)));
}

// ---------------- pass 1: softplus -> fp16 stage + raw-max partials --------
__global__ __launch_bounds__(THREADS) void pred_max_kernel(
        const float* __restrict__ x, float* __restrict__ partials,
        float* __restrict__ out) {
    const int chunk = blockIdx.x;
    const int t     = threadIdx.x;

    const f32x4* x4 = (const f32x4*)x + (size_t)chunk * F4_PER_BLOCK;
    // fp16 stage lives in the first 32 KB of this block's OWN out slot.
    f16x4* h4 = (f16x4*)((char*)out + (size_t)chunk * SLOT_BYTES);

    float m = -INFINITY;
#pragma unroll
    for (int b = 0; b < NBATCH; ++b) {
        f32x4 v[BATCH];
#pragma unroll
        for (int j = 0; j < BATCH; ++j)              // 4 loads back-to-back
            v[j] = x4[(size_t)(b * BATCH + j) * THREADS + t];
#pragma unroll
        for (int j = 0; j < BATCH; ++j) {
            m = fmaxf(m, fmaxf(fmaxf(v[j].x, v[j].y), fmaxf(v[j].z, v[j].w)));
            f16x4 h;
            h.x = (_Float16)softplus_f(v[j].x);
            h.y = (_Float16)softplus_f(v[j].y);
            h.z = (_Float16)softplus_f(v[j].z);
            h.w = (_Float16)softplus_f(v[j].w);
            h4[(size_t)(b * BATCH + j) * THREADS + t] = h;  // 8B store, own slot
        }
    }

    // wave64 shuffle reduction
#pragma unroll
    for (int off = 32; off > 0; off >>= 1)
        m = fmaxf(m, __shfl_down(m, off, 64));

    __shared__ float wmax[THREADS / 64];
    if ((t & 63) == 0) wmax[t >> 6] = m;
    __syncthreads();

    if (t == 0) {
        float bm = wmax[0];
#pragma unroll
        for (int w = 1; w < THREADS / 64; ++w) bm = fmaxf(bm, wmax[w]);
        partials[chunk] = bm;                        // raw max
    }
}

// ---------------- pass 2: pure stream: fp16 pred * scale -> fp32 out -------
__global__ __launch_bounds__(THREADS) void scale_kernel(
        const float* __restrict__ partials, float* __restrict__ out) {
    const int chunk  = blockIdx.x;
    const int sample = chunk / BLOCKS_PER_SAMPLE;
    const int t      = threadIdx.x;

    // ---- prologue: reduce this sample's 16 partials, broadcast scale ----
    __shared__ float s_scale;
    if (t < 64) {
        float p = (t < BLOCKS_PER_SAMPLE)
                    ? partials[sample * BLOCKS_PER_SAMPLE + t] : -INFINITY;
#pragma unroll
        for (int off = 8; off > 0; off >>= 1)      // butterfly within 16 lanes
            p = fmaxf(p, __shfl_xor(p, off, 64));
        if (t == 0) {
            float mm = softplus_f(p);              // mm > 0 always
            s_scale = (mm > 1e-8f) ? (1.0f / mm) : 1.0f;
        }
    }

    // ---- read ALL of this block's fp16 pred into registers ----
    const f16x8* hv = (const f16x8*)((const char*)out + (size_t)chunk * SLOT_BYTES);
    f16x8 ph[8];
#pragma unroll
    for (int j = 0; j < 8; ++j)                    // 8 x 16B coalesced loads
        ph[j] = hv[(size_t)j * THREADS + t];

    __syncthreads();                               // pred fully read; scale ready
    const float scale = s_scale;

    // ---- overwrite slot with scaled fp32 ----
    f32x4* o4 = (f32x4*)out + (size_t)chunk * F4_PER_BLOCK;
#pragma unroll
    for (int j = 0; j < 8; ++j) {
        // elements (j*256+t)*8 .. +7  ->  float4 indices 512*j + 2t, +1
        f32x4 a, b;
        a.x = (float)ph[j][0] * scale;
        a.y = (float)ph[j][1] * scale;
        a.z = (float)ph[j][2] * scale;
        a.w = (float)ph[j][3] * scale;
        b.x = (float)ph[j][4] * scale;
        b.y = (float)ph[j][5] * scale;
        b.z = (float)ph[j][6] * scale;
        b.w = (float)ph[j][7] * scale;
        const size_t f = (size_t)512 * j + 2 * t;
        o4[f]     = a;
        o4[f + 1] = b;
    }
}

extern "C" void kernel_launch(void* const* d_in, const int* in_sizes, int n_in,
                              void* d_out, int out_size, void* d_ws, size_t ws_size,
                              hipStream_t stream) {
    const float* x  = (const float*)d_in[0];
    float* out      = (float*)d_out;
    float* partials = (float*)d_ws;                 // 2048 floats, fully written

    const int n_total   = in_sizes[0];
    const int n_samples = n_total / PER_SAMPLE;          // 128
    const int grid      = n_samples * BLOCKS_PER_SAMPLE; // 2048 blocks

    pred_max_kernel<<<grid, THREADS, 0, stream>>>(x, partials, out);
    scale_kernel<<<grid, THREADS, 0, stream>>>(partials, out);
}

// Round 6
// 248.805 us; speedup vs baseline: 1.0377x; 1.0377x over previous
//
#include <hip/hip_runtime.h>
#include <math.h>

// Problem: x[128, 1, 512, 512] fp32.
//   pred = softplus(x); m = max(pred) per sample; out = m > 1e-8 ? pred/m : pred
// softplus is strictly monotone -> per-sample max of pred == softplus(raw max).
//
// R11: restore R7 champion (248.2 us e2e; ~100 us controllable vs ~145 us
// fixed harness poison/restore overhead). Structural alternatives all
// measured and rejected:
//   - fused single-dispatch with cross-block join: 250/160/110 us kernel-only
//     (R6 acquire-storm / R8 relaxed / R9 half-capacity co-resident) — join
//     overhead exceeds the ~20 us a second pass costs.
//   - nontemporal vs cacheable stores: neutral (R5 vs R7).
//   - descending XCD-congruent pass-2 order: neutral but harmless (kept).
//   - fp16 pred staging in out-slot: 258 us (-10 regression, extra 66 MB
//     store stream + L3 dirty-set overflow).
// Two-pass floor ~80-95 us (134 MB HBM read | 134 MB L3 read + 134 MB HBM
// write + 2 dispatch ramps); we sit within ~15% of it.

#define PER_SAMPLE (512 * 512)                       // 262144 floats / sample
#define F4_PER_SAMPLE (PER_SAMPLE / 4)               // 65536 float4
#define BLOCKS_PER_SAMPLE 16
#define THREADS 256
#define F4_PER_BLOCK (F4_PER_SAMPLE / BLOCKS_PER_SAMPLE) // 4096 float4
#define F4_PER_THREAD (F4_PER_BLOCK / THREADS)           // 16 float4 / thread
#define BATCH 4                                          // loads in flight

typedef float f32x4 __attribute__((ext_vector_type(4)));

__device__ __forceinline__ float softplus_f(float x) {
    // max(x,0) + log1p(exp(-|x|)); abs err ~6e-8 << 2e-2 threshold.
    return fmaxf(x, 0.0f) + __logf(1.0f + __expf(-fabsf(x)));
}

__global__ __launch_bounds__(THREADS) void rawmax_kernel(
        const float* __restrict__ x, float* __restrict__ partials) {
    const int sample = blockIdx.x / BLOCKS_PER_SAMPLE;
    const int part   = blockIdx.x % BLOCKS_PER_SAMPLE;
    const int t      = threadIdx.x;

    const f32x4* x4 = (const f32x4*)x +
        (size_t)sample * F4_PER_SAMPLE + (size_t)part * F4_PER_BLOCK;

    float m = -INFINITY;
#pragma unroll
    for (int b = 0; b < F4_PER_THREAD / BATCH; ++b) {
        f32x4 v[BATCH];
#pragma unroll
        for (int j = 0; j < BATCH; ++j)              // 4 loads back-to-back
            v[j] = x4[(size_t)(b * BATCH + j) * THREADS + t];
#pragma unroll
        for (int j = 0; j < BATCH; ++j)
            m = fmaxf(m, fmaxf(fmaxf(v[j].x, v[j].y), fmaxf(v[j].z, v[j].w)));
    }

    // wave64 shuffle reduction
#pragma unroll
    for (int off = 32; off > 0; off >>= 1)
        m = fmaxf(m, __shfl_down(m, off, 64));

    __shared__ float wmax[THREADS / 64];
    if ((t & 63) == 0) wmax[t >> 6] = m;
    __syncthreads();

    if (t == 0) {
        float bm = wmax[0];
#pragma unroll
        for (int w = 1; w < THREADS / 64; ++w) bm = fmaxf(bm, wmax[w]);
        partials[blockIdx.x] = bm;   // raw max, softplus deferred to pass B
    }
}

__global__ __launch_bounds__(THREADS) void scale_kernel(
        const float* __restrict__ x, const float* __restrict__ partials,
        float* __restrict__ out, int n_chunks) {
    // Descending chunk order, XCD-congruent: chunk == blockIdx (mod 8), so
    // this block reads data whose pass-1 block ran on the SAME XCD, and the
    // first-scheduled pass-2 blocks hit what pass 1 left in L2 last.
    const int b     = blockIdx.x;
    const int chunk = (n_chunks - 8 - (b & ~7)) | (b & 7);
    const int sample = chunk / BLOCKS_PER_SAMPLE;
    const int part   = chunk % BLOCKS_PER_SAMPLE;
    const int t      = threadIdx.x;

    // ---- prologue: reduce this sample's 16 partials, broadcast scale ----
    __shared__ float s_scale;
    if (t < 64) {
        float p = (t < BLOCKS_PER_SAMPLE)
                    ? partials[sample * BLOCKS_PER_SAMPLE + t] : -INFINITY;
#pragma unroll
        for (int off = 8; off > 0; off >>= 1)      // butterfly within 16 lanes
            p = fmaxf(p, __shfl_xor(p, off, 64));
        if (t == 0) {
            float m = softplus_f(p);               // m > 0 always
            s_scale = (m > 1e-8f) ? (1.0f / m) : 1.0f;
        }
    }
    __syncthreads();
    const float scale = s_scale;

    // ---- streaming softplus * scale; cacheable stores (lazy writeback) ----
    const size_t base =
        (size_t)sample * F4_PER_SAMPLE + (size_t)part * F4_PER_BLOCK;
    const f32x4* x4 = (const f32x4*)x + base;
    f32x4* o4       = (f32x4*)out + base;

#pragma unroll
    for (int b2 = 0; b2 < F4_PER_THREAD / BATCH; ++b2) {
        f32x4 v[BATCH];
#pragma unroll
        for (int j = 0; j < BATCH; ++j)              // 4 loads back-to-back
            v[j] = x4[(size_t)(b2 * BATCH + j) * THREADS + t];
#pragma unroll
        for (int j = 0; j < BATCH; ++j) {
            f32x4 r;
            r.x = softplus_f(v[j].x) * scale;
            r.y = softplus_f(v[j].y) * scale;
            r.z = softplus_f(v[j].z) * scale;
            r.w = softplus_f(v[j].w) * scale;
            o4[(size_t)(b2 * BATCH + j) * THREADS + t] = r;  // cacheable
        }
    }
}

extern "C" void kernel_launch(void* const* d_in, const int* in_sizes, int n_in,
                              void* d_out, int out_size, void* d_ws, size_t ws_size,
                              hipStream_t stream) {
    const float* x  = (const float*)d_in[0];
    float* out      = (float*)d_out;
    float* partials = (float*)d_ws;                 // 2048 floats, fully written

    const int n_total   = in_sizes[0];
    const int n_samples = n_total / PER_SAMPLE;          // 128
    const int grid      = n_samples * BLOCKS_PER_SAMPLE; // 2048 blocks

    rawmax_kernel<<<grid, THREADS, 0, stream>>>(x, partials);
    scale_kernel<<<grid, THREADS, 0, stream>>>(x, partials, out, grid);
}